// Round 7
// baseline (89.346 us; speedup 1.0000x reference)
//
#include <hip/hip_runtime.h>
#include <hip/hip_bf16.h>
#include <math.h>

// out[b,i,j,o] = lrelu( sum_k pe[d_k]@W_k[:,o] + b[o] ),  d_k from pos_s/pos_e.
// Key algebra: ei = si + di, di = span in [0,16). Define (bias folded into P):
//   P[d][r][o] = Y0[r][o] + Y2[r+d][o],  Q[d][r][o] = Y1[r][o] + Y3[r+d][o]
// then out[b,i,j] = lrelu( P[di][si-sj+ML] + Q[di][si-ej+ML] )  -- 2 gathers not 4.
// Pipeline: (1) Y fp32 (4.2 MB), (2) P/Q bf16 (16 deltas, 16.8 MB, L3-resident),
// (3) fused gather: 1 KB read per 1 KB written, NT stores.

typedef float f32x4 __attribute__((ext_vector_type(4)));

__device__ __forceinline__ float lrelu(float x) { return fmaxf(x, 0.01f * x); }
__device__ __forceinline__ float bflo(unsigned int v) {
    union { unsigned int i; float f; } c; c.i = v << 16; return c.f;
}
__device__ __forceinline__ float bfhi(unsigned int v) {
    union { unsigned int i; float f; } c; c.i = v & 0xffff0000u; return c.f;
}

// ---------------- Kernel 1: Y precompute in fp32 (R4 structure) ---------------
__global__ __launch_bounds__(256) void precompute_Yf(
        const float* __restrict__ pe, const float* __restrict__ W,
        const float* __restrict__ bias, float* __restrict__ Yf, int NPE) {
    const int H = 256;
    const int ntile = (NPE + 7) >> 3;
    const int k  = blockIdx.x / ntile;
    const int r0 = (blockIdx.x % ntile) << 3;
    const int o  = threadIdx.x;
    const float* __restrict__ Wk = W + (size_t)k * H * H;

    int rows[8];
#pragma unroll
    for (int r = 0; r < 8; ++r) rows[r] = min(r0 + r, NPE - 1);
    float acc[8];
#pragma unroll
    for (int r = 0; r < 8; ++r) acc[r] = 0.f;

#pragma unroll 2
    for (int h = 0; h < 256; h += 4) {
        const float w0 = Wk[(h + 0) * H + o];
        const float w1 = Wk[(h + 1) * H + o];
        const float w2 = Wk[(h + 2) * H + o];
        const float w3 = Wk[(h + 3) * H + o];
#pragma unroll
        for (int r = 0; r < 8; ++r) {
            const f32x4 p = *reinterpret_cast<const f32x4*>(&pe[rows[r] * H + h]);
            acc[r] += p.x * w0 + p.y * w1 + p.z * w2 + p.w * w3;
        }
    }
    const float bv = (k == 0) ? bias[o] : 0.f;
#pragma unroll
    for (int r = 0; r < 8; ++r) {
        const int rr = r0 + r;
        if (rr < NPE) Yf[((size_t)k * NPE + rr) * H + o] = acc[r] + bv;
    }
}

// ---------------- Kernel 2: build P/Q bf16 tables -----------------------------
// T slot g = (d*2 + p)*NPE + row ; P(p=0)=Y0[row]+Y2[row+d], Q(p=1)=Y1+Y3[+d].
// 4 rows per block of 256 threads (thread = col o), all loads/stores coalesced.
__global__ __launch_bounds__(256) void build_PQ(
        const float* __restrict__ Yf, __hip_bfloat16* __restrict__ T,
        int NPE, int ND) {
    const int o = threadIdx.x;
    const int g0 = blockIdx.x << 2;
    const int total = ND * 2 * NPE;
#pragma unroll
    for (int m = 0; m < 4; ++m) {
        const int g = g0 + m;
        if (g >= total) return;
        const int d   = g / (2 * NPE);
        const int rem = g - d * (2 * NPE);
        const int p   = rem / NPE;
        const int row = rem - p * NPE;
        const int rowB = min(row + d, NPE - 1);
        const float a = Yf[((size_t)(p + 0) * NPE + row)  * 256 + o];
        const float b = Yf[((size_t)(p + 2) * NPE + rowB) * 256 + o];
        T[(size_t)g * 256 + o] = __float2bfloat16(a + b);
    }
}

// ---------------- Kernel 3: fused gather (R4 winning shape) -------------------
// block = 256 = 4 waves; wave w: j = jbase + 2w + {0,1}; 64 lanes/row (4 cols
// per lane). 2 x 8B bf16 loads + 1 x 16B NT store per j. Chunked XCD swizzle.
__global__ __launch_bounds__(256) void gather_fused(
        const int* __restrict__ pos_s, const int* __restrict__ pos_e,
        const __hip_bfloat16* __restrict__ T, const float* __restrict__ Yf,
        float* __restrict__ out, int S, int ML, int NPE, int ND) {
    int lb = blockIdx.x;
    if ((gridDim.x & 7) == 0)
        lb = (blockIdx.x & 7) * (gridDim.x >> 3) + (blockIdx.x >> 3);

    const int t  = threadIdx.x;
    const int w  = t >> 6;
    const int ln = t & 63;
    const int S8 = S >> 3;

    const int jbase = (lb % S8) << 3;
    const int i     = (lb / S8) % S;
    const int bb    = lb / (S8 * S);
    const int j0    = jbase + (w << 1);
    const int j1    = j0 + 1;

    const int si = pos_s[bb * S + i];
    const int ei = pos_e[bb * S + i];
    const int di = ei - si;

    const int sj0 = pos_s[bb * S + j0];
    const int ej0 = pos_e[bb * S + j0];
    const int sj1 = pos_s[bb * S + j1];
    const int ej1 = pos_e[bb * S + j1];

    const size_t orow = ((size_t)bb * S + i) * S;
    f32x4* __restrict__ ov = reinterpret_cast<f32x4*>(out);

    if (di >= 0 && di < ND) {           // uniform per block
        const int pb = (di * 2 + 0) * NPE + si + ML;   // P base (subtract sj)
        const int qb = (di * 2 + 1) * NPE + si + ML;   // Q base (subtract ej)
        const uint2* __restrict__ Tv = reinterpret_cast<const uint2*>(T);

        const uint2 uP0 = Tv[((size_t)(pb - sj0) << 6) + ln];
        const uint2 uQ0 = Tv[((size_t)(qb - ej0) << 6) + ln];
        const uint2 uP1 = Tv[((size_t)(pb - sj1) << 6) + ln];
        const uint2 uQ1 = Tv[((size_t)(qb - ej1) << 6) + ln];

        f32x4 v0, v1;
        v0.x = lrelu(bflo(uP0.x) + bflo(uQ0.x));
        v0.y = lrelu(bfhi(uP0.x) + bfhi(uQ0.x));
        v0.z = lrelu(bflo(uP0.y) + bflo(uQ0.y));
        v0.w = lrelu(bfhi(uP0.y) + bfhi(uQ0.y));
        v1.x = lrelu(bflo(uP1.x) + bflo(uQ1.x));
        v1.y = lrelu(bfhi(uP1.x) + bfhi(uQ1.x));
        v1.z = lrelu(bflo(uP1.y) + bflo(uQ1.y));
        v1.w = lrelu(bfhi(uP1.y) + bfhi(uQ1.y));

        __builtin_nontemporal_store(v0, &ov[((orow + j0) << 6) + ln]);
        __builtin_nontemporal_store(v1, &ov[((orow + j1) << 6) + ln]);
    } else {                             // safety path (never taken for harness data)
        const f32x4* __restrict__ Yv = reinterpret_cast<const f32x4*>(Yf);
        const int a0 = 0 * NPE + si - sj0 + ML, a1 = 1 * NPE + si - ej0 + ML;
        const int a2 = 2 * NPE + ei - sj0 + ML, a3 = 3 * NPE + ei - ej0 + ML;
        const int b0 = 0 * NPE + si - sj1 + ML, b1 = 1 * NPE + si - ej1 + ML;
        const int b2 = 2 * NPE + ei - sj1 + ML, b3 = 3 * NPE + ei - ej1 + ML;
        const f32x4 A0 = Yv[((size_t)a0 << 6) + ln], A1 = Yv[((size_t)a1 << 6) + ln];
        const f32x4 A2 = Yv[((size_t)a2 << 6) + ln], A3 = Yv[((size_t)a3 << 6) + ln];
        const f32x4 B0 = Yv[((size_t)b0 << 6) + ln], B1 = Yv[((size_t)b1 << 6) + ln];
        const f32x4 B2 = Yv[((size_t)b2 << 6) + ln], B3 = Yv[((size_t)b3 << 6) + ln];
        f32x4 v0, v1;
        v0.x = lrelu(A0.x + A1.x + A2.x + A3.x);
        v0.y = lrelu(A0.y + A1.y + A2.y + A3.y);
        v0.z = lrelu(A0.z + A1.z + A2.z + A3.z);
        v0.w = lrelu(A0.w + A1.w + A2.w + A3.w);
        v1.x = lrelu(B0.x + B1.x + B2.x + B3.x);
        v1.y = lrelu(B0.y + B1.y + B2.y + B3.y);
        v1.z = lrelu(B0.z + B1.z + B2.z + B3.z);
        v1.w = lrelu(B0.w + B1.w + B2.w + B3.w);
        __builtin_nontemporal_store(v0, &ov[((orow + j0) << 6) + ln]);
        __builtin_nontemporal_store(v1, &ov[((orow + j1) << 6) + ln]);
    }
}

// ---------------- Fallback tier 1: R4 path (bf16 Y, 4-row gather) -------------
__global__ __launch_bounds__(256) void precompute_Yb(
        const float* __restrict__ pe, const float* __restrict__ W,
        const float* __restrict__ bias, __hip_bfloat16* __restrict__ Y, int NPE) {
    const int H = 256;
    const int ntile = (NPE + 7) >> 3;
    const int k  = blockIdx.x / ntile;
    const int r0 = (blockIdx.x % ntile) << 3;
    const int o  = threadIdx.x;
    const float* __restrict__ Wk = W + (size_t)k * H * H;
    int rows[8];
#pragma unroll
    for (int r = 0; r < 8; ++r) rows[r] = min(r0 + r, NPE - 1);
    float acc[8];
#pragma unroll
    for (int r = 0; r < 8; ++r) acc[r] = 0.f;
#pragma unroll 2
    for (int h = 0; h < 256; h += 4) {
        const float w0 = Wk[(h + 0) * H + o];
        const float w1 = Wk[(h + 1) * H + o];
        const float w2 = Wk[(h + 2) * H + o];
        const float w3 = Wk[(h + 3) * H + o];
#pragma unroll
        for (int r = 0; r < 8; ++r) {
            const f32x4 p = *reinterpret_cast<const f32x4*>(&pe[rows[r] * H + h]);
            acc[r] += p.x * w0 + p.y * w1 + p.z * w2 + p.w * w3;
        }
    }
    const float bv = (k == 0) ? bias[o] : 0.f;
#pragma unroll
    for (int r = 0; r < 8; ++r) {
        const int rr = r0 + r;
        if (rr < NPE) Y[((size_t)k * NPE + rr) * H + o] = __float2bfloat16(acc[r] + bv);
    }
}

__global__ __launch_bounds__(256) void gather2(
        const int* __restrict__ pos_s, const int* __restrict__ pos_e,
        const __hip_bfloat16* __restrict__ Y, float* __restrict__ out,
        int S, int ML, int NPE) {
    const int t  = threadIdx.x;
    const int w  = t >> 6;
    const int ln = t & 63;
    const int S8 = S >> 3;
    const int jbase = (blockIdx.x % S8) << 3;
    const int i     = (blockIdx.x / S8) % S;
    const int bb    = blockIdx.x / (S8 * S);
    const int j0    = jbase + (w << 1);
    const int j1    = j0 + 1;
    const int si = pos_s[bb * S + i];
    const int ei = pos_e[bb * S + i];
    const int sj0 = pos_s[bb * S + j0];
    const int ej0 = pos_e[bb * S + j0];
    const int sj1 = pos_s[bb * S + j1];
    const int ej1 = pos_e[bb * S + j1];
    const uint2* __restrict__ Yv = reinterpret_cast<const uint2*>(Y);
#define YIDX(r) (((size_t)(r) << 6) + ln)
    const int a0 = 0 * NPE + si - sj0 + ML, a1 = 1 * NPE + si - ej0 + ML;
    const int a2 = 2 * NPE + ei - sj0 + ML, a3 = 3 * NPE + ei - ej0 + ML;
    const int b0 = 0 * NPE + si - sj1 + ML, b1 = 1 * NPE + si - ej1 + ML;
    const int b2 = 2 * NPE + ei - sj1 + ML, b3 = 3 * NPE + ei - ej1 + ML;
    const uint2 uA0 = Yv[YIDX(a0)], uA1 = Yv[YIDX(a1)],
                uA2 = Yv[YIDX(a2)], uA3 = Yv[YIDX(a3)];
    const uint2 uB0 = Yv[YIDX(b0)], uB1 = Yv[YIDX(b1)],
                uB2 = Yv[YIDX(b2)], uB3 = Yv[YIDX(b3)];
#undef YIDX
    f32x4 vA, vB;
    vA.x = lrelu(bflo(uA0.x) + bflo(uA1.x) + bflo(uA2.x) + bflo(uA3.x));
    vA.y = lrelu(bfhi(uA0.x) + bfhi(uA1.x) + bfhi(uA2.x) + bfhi(uA3.x));
    vA.z = lrelu(bflo(uA0.y) + bflo(uA1.y) + bflo(uA2.y) + bflo(uA3.y));
    vA.w = lrelu(bfhi(uA0.y) + bfhi(uA1.y) + bfhi(uA2.y) + bfhi(uA3.y));
    vB.x = lrelu(bflo(uB0.x) + bflo(uB1.x) + bflo(uB2.x) + bflo(uB3.x));
    vB.y = lrelu(bfhi(uB0.x) + bfhi(uB1.x) + bfhi(uB2.x) + bfhi(uB3.x));
    vB.z = lrelu(bflo(uB0.y) + bflo(uB1.y) + bflo(uB2.y) + bflo(uB3.y));
    vB.w = lrelu(bfhi(uB0.y) + bfhi(uB1.y) + bfhi(uB2.y) + bfhi(uB3.y));
    const size_t orow = ((size_t)bb * S + i) * S;
    f32x4* __restrict__ ov = reinterpret_cast<f32x4*>(out);
    __builtin_nontemporal_store(vA, &ov[((orow + j0) << 6) + ln]);
    __builtin_nontemporal_store(vB, &ov[((orow + j1) << 6) + ln]);
}

// ---------------- Fallback tier 2: direct ------------------------------------
__global__ void direct_kernel(const int* __restrict__ pos_s,
                              const int* __restrict__ pos_e,
                              const float* __restrict__ pe,
                              const float* __restrict__ W,
                              const float* __restrict__ bias,
                              float* __restrict__ out,
                              int B, int S, int H, int ML) {
    const int blk = blockIdx.x;
    const int j   = blk % S;
    const int i   = (blk / S) % S;
    const int bb  = blk / (S * S);
    const int o   = threadIdx.x;
    const int si = pos_s[bb * S + i];
    const int ei = pos_e[bb * S + i];
    const int sj = pos_s[bb * S + j];
    const int ej = pos_e[bb * S + j];
    const int rss = si - sj + ML, rse = si - ej + ML;
    const int res = ei - sj + ML, ree = ei - ej + ML;
    float acc = bias[o];
    for (int h = 0; h < H; ++h) {
        acc += pe[rss * H + h] * W[(0 * H + h) * H + o];
        acc += pe[rse * H + h] * W[(1 * H + h) * H + o];
        acc += pe[res * H + h] * W[(2 * H + h) * H + o];
        acc += pe[ree * H + h] * W[(3 * H + h) * H + o];
    }
    out[(((size_t)bb * S + i) * S + j) * H + o] = lrelu(acc);
}

extern "C" void kernel_launch(void* const* d_in, const int* in_sizes, int n_in,
                              void* d_out, int out_size, void* d_ws, size_t ws_size,
                              hipStream_t stream) {
    const int*   pos_s = (const int*)d_in[0];
    const int*   pos_e = (const int*)d_in[1];
    const float* pe    = (const float*)d_in[2];
    const float* W     = (const float*)d_in[3];
    const float* bias  = (const float*)d_in[4];
    float*       out   = (float*)d_out;

    const int H   = in_sizes[4];                 // 256
    const int NPE = in_sizes[2] / H;             // 1025
    const int ML  = (NPE - 1) / 2;               // 512
    const int BS  = in_sizes[0];
    const int S   = (int)((long long)out_size / ((long long)BS * H)); // 256
    const int B   = BS / S;
    const int ND  = 16;                          // span range [0,16)

    const size_t yf_bytes = (size_t)4 * NPE * 256 * sizeof(float);          // 4.2 MB
    const size_t yf_al    = (yf_bytes + 255) & ~(size_t)255;
    const size_t t_bytes  = (size_t)ND * 2 * NPE * 256 * sizeof(__hip_bfloat16); // 16.8 MB
    const size_t yb_bytes = (size_t)4 * NPE * 256 * sizeof(__hip_bfloat16); // 2.1 MB

    if (H == 256 && (S & 7) == 0 && ws_size >= yf_al + t_bytes) {
        float*          Yf = (float*)d_ws;
        __hip_bfloat16* T  = (__hip_bfloat16*)((char*)d_ws + yf_al);
        const int ntile = (NPE + 7) >> 3;
        precompute_Yf<<<4 * ntile, 256, 0, stream>>>(pe, W, bias, Yf, NPE);
        const int rowsT = ND * 2 * NPE;
        build_PQ<<<(rowsT + 3) >> 2, 256, 0, stream>>>(Yf, T, NPE, ND);
        const int nblk = B * S * (S >> 3);
        gather_fused<<<nblk, 256, 0, stream>>>(pos_s, pos_e, T, Yf, out,
                                               S, ML, NPE, ND);
    } else if (H == 256 && (S & 7) == 0 && ws_size >= yb_bytes) {
        __hip_bfloat16* Y = (__hip_bfloat16*)d_ws;
        const int ntile = (NPE + 7) >> 3;
        precompute_Yb<<<4 * ntile, 256, 0, stream>>>(pe, W, bias, Y, NPE);
        const int nblk = B * S * (S >> 3);
        gather2<<<nblk, 256, 0, stream>>>(pos_s, pos_e, Y, out, S, ML, NPE);
    } else {
        direct_kernel<<<B * S * S, H, 0, stream>>>(pos_s, pos_e, pe, W, bias, out,
                                                   B, S, H, ML);
    }
}

// Round 8
// 55.658 us; speedup vs baseline: 1.6053x; 1.6053x over previous
//
#include <hip/hip_runtime.h>
#include <hip/hip_bf16.h>
#include <math.h>

// out[b,i,j,o] = lrelu( sum_k pe[d_k]@W_k[:,o] + b[o] )
// (1) Y[k][r][o] = pe[r,:]@W_k[:,o] (+bias at k==0), fp32 math, bf16 store.
//     Table = 2.1 MB -> fits each XCD's 4 MiB L2 (R7 proved >4 MB tables lose).
// (2) gather: wave owns 4 j's; ALL 16 row-loads issued first (no store-load
//     interleave -> no in-order vmcnt serialization), then convert+lrelu,
//     then 4 x 1KB coalesced NT stores.

typedef float f32x4 __attribute__((ext_vector_type(4)));

__device__ __forceinline__ float lrelu(float x) { return fmaxf(x, 0.01f * x); }
__device__ __forceinline__ float bflo(unsigned int v) {
    union { unsigned int i; float f; } c; c.i = v << 16; return c.f;
}
__device__ __forceinline__ float bfhi(unsigned int v) {
    union { unsigned int i; float f; } c; c.i = v & 0xffff0000u; return c.f;
}

// ---------------- Kernel 1: Y precompute (exact R4 version, 52.1us config) ----
__global__ __launch_bounds__(256) void precompute_Y(
        const float* __restrict__ pe, const float* __restrict__ W,
        const float* __restrict__ bias, __hip_bfloat16* __restrict__ Y, int NPE) {
    const int H = 256;
    const int ntile = (NPE + 7) >> 3;
    const int k  = blockIdx.x / ntile;
    const int r0 = (blockIdx.x % ntile) << 3;
    const int o  = threadIdx.x;
    const float* __restrict__ Wk = W + (size_t)k * H * H;

    int rows[8];
#pragma unroll
    for (int r = 0; r < 8; ++r) rows[r] = min(r0 + r, NPE - 1);
    float acc[8];
#pragma unroll
    for (int r = 0; r < 8; ++r) acc[r] = 0.f;

#pragma unroll 2
    for (int h = 0; h < 256; h += 4) {
        const float w0 = Wk[(h + 0) * H + o];
        const float w1 = Wk[(h + 1) * H + o];
        const float w2 = Wk[(h + 2) * H + o];
        const float w3 = Wk[(h + 3) * H + o];
#pragma unroll
        for (int r = 0; r < 8; ++r) {
            const f32x4 p = *reinterpret_cast<const f32x4*>(&pe[rows[r] * H + h]);
            acc[r] += p.x * w0 + p.y * w1 + p.z * w2 + p.w * w3;
        }
    }
    const float bv = (k == 0) ? bias[o] : 0.f;
#pragma unroll
    for (int r = 0; r < 8; ++r) {
        const int rr = r0 + r;
        if (rr < NPE)
            Y[((size_t)k * NPE + rr) * H + o] = __float2bfloat16(acc[r] + bv);
    }
}

// ---------------- Kernel 2: gather, 4 j's per wave, batched loads --------------
// block = 256 = 4 waves; block covers (bb, i, 16 j's); wave w owns 4 j's.
// Per lane: 16 uint2 loads (all issued before any store), 32 f32 outputs,
// 4 NT f32x4 stores. Grid = B*S*(S/16).
__global__ __launch_bounds__(256) void gather4(
        const int* __restrict__ pos_s, const int* __restrict__ pos_e,
        const __hip_bfloat16* __restrict__ Y, float* __restrict__ out,
        int S, int ML, int NPE) {
    const int t   = threadIdx.x;
    const int w   = t >> 6;
    const int ln  = t & 63;
    const int S16 = S >> 4;

    const int jb16 = (blockIdx.x % S16) << 4;
    const int i    = (blockIdx.x / S16) % S;
    const int bb   = blockIdx.x / (S16 * S);
    const int j0   = jb16 + (w << 2);          // this wave's first j

    const int si = pos_s[bb * S + i];
    const int ei = pos_e[bb * S + i];
    const int base0 = 0 * NPE + si + ML;       // subtract sj
    const int base1 = 1 * NPE + si + ML;       // subtract ej
    const int base2 = 2 * NPE + ei + ML;       // subtract sj
    const int base3 = 3 * NPE + ei + ML;       // subtract ej

    int sj[4], ej[4];
#pragma unroll
    for (int n = 0; n < 4; ++n) {
        sj[n] = pos_s[bb * S + j0 + n];
        ej[n] = pos_e[bb * S + j0 + n];
    }

    const uint2* __restrict__ Yv = reinterpret_cast<const uint2*>(Y);

    // Issue all 16 independent loads before any use.
    uint2 u[4][4];
#pragma unroll
    for (int n = 0; n < 4; ++n) {
        u[n][0] = Yv[((size_t)(base0 - sj[n]) << 6) + ln];
        u[n][1] = Yv[((size_t)(base1 - ej[n]) << 6) + ln];
        u[n][2] = Yv[((size_t)(base2 - sj[n]) << 6) + ln];
        u[n][3] = Yv[((size_t)(base3 - ej[n]) << 6) + ln];
    }

    const size_t orow = ((size_t)bb * S + i) * S;
    f32x4* __restrict__ ov = reinterpret_cast<f32x4*>(out);

#pragma unroll
    for (int n = 0; n < 4; ++n) {
        f32x4 v;
        v.x = lrelu(bflo(u[n][0].x) + bflo(u[n][1].x) + bflo(u[n][2].x) + bflo(u[n][3].x));
        v.y = lrelu(bfhi(u[n][0].x) + bfhi(u[n][1].x) + bfhi(u[n][2].x) + bfhi(u[n][3].x));
        v.z = lrelu(bflo(u[n][0].y) + bflo(u[n][1].y) + bflo(u[n][2].y) + bflo(u[n][3].y));
        v.w = lrelu(bfhi(u[n][0].y) + bfhi(u[n][1].y) + bfhi(u[n][2].y) + bfhi(u[n][3].y));
        __builtin_nontemporal_store(v, &ov[((orow + j0 + n) << 6) + ln]);
    }
}

// ---------------- Fallback: direct compute (ws too small / odd shapes) --------
__global__ void direct_kernel(const int* __restrict__ pos_s,
                              const int* __restrict__ pos_e,
                              const float* __restrict__ pe,
                              const float* __restrict__ W,
                              const float* __restrict__ bias,
                              float* __restrict__ out,
                              int B, int S, int H, int ML) {
    const int blk = blockIdx.x;
    const int j   = blk % S;
    const int i   = (blk / S) % S;
    const int bb  = blk / (S * S);
    const int o   = threadIdx.x;
    const int si = pos_s[bb * S + i];
    const int ei = pos_e[bb * S + i];
    const int sj = pos_s[bb * S + j];
    const int ej = pos_e[bb * S + j];
    const int rss = si - sj + ML, rse = si - ej + ML;
    const int res = ei - sj + ML, ree = ei - ej + ML;
    float acc = bias[o];
    for (int h = 0; h < H; ++h) {
        acc += pe[rss * H + h] * W[(0 * H + h) * H + o];
        acc += pe[rse * H + h] * W[(1 * H + h) * H + o];
        acc += pe[res * H + h] * W[(2 * H + h) * H + o];
        acc += pe[ree * H + h] * W[(3 * H + h) * H + o];
    }
    out[(((size_t)bb * S + i) * S + j) * H + o] = lrelu(acc);
}

extern "C" void kernel_launch(void* const* d_in, const int* in_sizes, int n_in,
                              void* d_out, int out_size, void* d_ws, size_t ws_size,
                              hipStream_t stream) {
    const int*   pos_s = (const int*)d_in[0];
    const int*   pos_e = (const int*)d_in[1];
    const float* pe    = (const float*)d_in[2];
    const float* W     = (const float*)d_in[3];
    const float* bias  = (const float*)d_in[4];
    float*       out   = (float*)d_out;

    const int H   = in_sizes[4];                 // 256
    const int NPE = in_sizes[2] / H;             // 1025
    const int ML  = (NPE - 1) / 2;               // 512
    const int BS  = in_sizes[0];
    const int S   = (int)((long long)out_size / ((long long)BS * H)); // 256
    const int B   = BS / S;

    const size_t ybytes = (size_t)4 * NPE * 256 * sizeof(__hip_bfloat16); // 2.1 MB

    if (H == 256 && (S & 15) == 0 && ws_size >= ybytes) {
        __hip_bfloat16* Y = (__hip_bfloat16*)d_ws;
        const int ntile = (NPE + 7) >> 3;
        precompute_Y<<<4 * ntile, 256, 0, stream>>>(pe, W, bias, Y, NPE);
        const int nblk = B * S * (S >> 4);
        gather4<<<nblk, 256, 0, stream>>>(pos_s, pos_e, Y, out, S, ML, NPE);
    } else {
        direct_kernel<<<B * S * S, H, 0, stream>>>(pos_s, pos_e, pe, W, bias, out,
                                                   B, S, H, ML);
    }
}